// Round 3
// baseline (863.696 us; speedup 1.0000x reference)
//
#include <hip/hip_runtime.h>
#include <stdint.h>

// ---------- bf16 helpers (raw ushort storage) ----------
__device__ __forceinline__ float bf2f(unsigned short h) {
    union { unsigned int u; float f; } x;
    x.u = ((unsigned int)h) << 16;
    return x.f;
}
__device__ __forceinline__ unsigned short f2bf(float f) {
    union { float f; unsigned int u; } x;
    x.f = f;
    unsigned int u = x.u;
    unsigned int r = (u + 0x7FFFu + ((u >> 16) & 1u)) >> 16;  // RNE
    return (unsigned short)r;
}
// flag-aware scalar load: src is fp32 if f32 else bf16
__device__ __forceinline__ float ldf(const void* p, size_t i, int f32) {
    return f32 ? ((const float*)p)[i] : bf2f(((const unsigned short*)p)[i]);
}

typedef __attribute__((ext_vector_type(8))) short short8;
typedef __attribute__((ext_vector_type(4))) float floatx4;

// ---------- dtype detect: fp32 reinterpreted as bf16 shows huge exponents ----------
__global__ void k_detect(const unsigned short* __restrict__ p, int* flag) {
    __shared__ int cnt;
    if (threadIdx.x == 0) cnt = 0;
    __syncthreads();
    int c = 0;
    for (int i = threadIdx.x; i < 4096; i += 256) {
        unsigned e = (p[i] >> 7) & 0xFFu;
        if (e >= 0xC0u) c++;   // |x| >= 2^65 — impossible for N(0,1) bf16
    }
    atomicAdd(&cnt, c);
    __syncthreads();
    if (threadIdx.x == 0) *flag = (cnt > 32) ? 1 : 0;
}

// ---------------------------------------------------------------------------
// Tiled MFMA GEMM:
//   C[M,Nc](bf16) = act( [A0|A1|A2][M,K] * Bt[Nc,K](bf16)^T + bias )
// A parts: part p covers k in [256p, 256p+256), given as base pointer + element
// offset (offset applied in the A dtype: fp32 if dflag says so, else bf16).
// Bt / bias are always bf16 (pre-converted). BM=128, BK=64, 256 thr = 4 waves.
// ---------------------------------------------------------------------------
template <int BN>
__global__ __launch_bounds__(256) void gemm_nt(
    const void* __restrict__ A0, const void* __restrict__ A1,
    const void* __restrict__ A2, int o0, int o1, int o2, int lda,
    const unsigned short* __restrict__ Bt, int ldb,
    unsigned short* __restrict__ C, int ldc,
    const unsigned short* __restrict__ bias,
    int M, int K, int act, const int* __restrict__ dflag)
{
    constexpr int BM = 128, BK = 64;
    constexpr int NJ = (BN == 128) ? 4 : 2;
    const int af32 = dflag ? *dflag : 0;
    const int tid  = threadIdx.x;
    const int wave = tid >> 6;
    const int lane = tid & 63;
    const int quad = lane >> 4;
    const int l16  = lane & 15;
    const int m0   = blockIdx.x * BM;
    const int n0   = blockIdx.y * BN;
    const int wm   = (wave & 1) * 64;
    const int wn   = (wave >> 1) * (BN / 2);

    __shared__ short8 As[8 * (BM + 2)];
    __shared__ short8 Bs[8 * (BN + 2)];

    floatx4 acc[4][NJ];
#pragma unroll
    for (int i = 0; i < 4; i++)
#pragma unroll
        for (int j = 0; j < NJ; j++) acc[i][j] = (floatx4){0.f, 0.f, 0.f, 0.f};

    for (int kt = 0; kt < K; kt += BK) {
        const void* Ap = (kt < 256) ? A0 : (kt < 512) ? A1 : A2;
        const int Ao = (kt < 256) ? o0 : (kt < 512) ? o1 : o2;
        const int ko = kt & 255;
        // stage A: 128 rows x 8 chunks(16 bf16-bytes) = 1024 chunks, 4/thread
#pragma unroll
        for (int c = 0; c < 4; c++) {
            int lin = c * 256 + tid;
            int row = lin >> 3, kq = lin & 7;
            int gr = m0 + row; if (gr > M - 1) gr = M - 1;
            size_t eoff = (size_t)gr * lda + Ao + ko + kq * 8;
            short8 v;
            if (af32) {
                const float* pf = (const float*)Ap + eoff;
#pragma unroll
                for (int z = 0; z < 8; z++) v[z] = (short)f2bf(pf[z]);
            } else {
                v = *(const short8*)((const unsigned short*)Ap + eoff);
            }
            As[kq * (BM + 2) + row] = v;
        }
        // stage B (always bf16)
#pragma unroll
        for (int c = 0; c < (BN * 8) / 256; c++) {
            int lin = c * 256 + tid;
            int n = lin >> 3, kq = lin & 7;
            short8 v = *(const short8*)(Bt + (size_t)(n0 + n) * ldb + kt + kq * 8);
            Bs[kq * (BN + 2) + n] = v;
        }
        __syncthreads();
#pragma unroll
        for (int s = 0; s < 2; s++) {
            short8 af[4], bfr[NJ];
#pragma unroll
            for (int i = 0; i < 4; i++)
                af[i] = As[(s * 4 + quad) * (BM + 2) + wm + i * 16 + l16];
#pragma unroll
            for (int j = 0; j < NJ; j++)
                bfr[j] = Bs[(s * 4 + quad) * (BN + 2) + wn + j * 16 + l16];
#pragma unroll
            for (int i = 0; i < 4; i++)
#pragma unroll
                for (int j = 0; j < NJ; j++)
                    acc[i][j] = __builtin_amdgcn_mfma_f32_16x16x32_bf16(
                        af[i], bfr[j], acc[i][j], 0, 0, 0);
        }
        __syncthreads();
    }

    // epilogue: C/D layout col = lane&15, row = quad*4 + reg  [m89-verified]
#pragma unroll
    for (int j = 0; j < NJ; j++) {
        int gc = n0 + wn + j * 16 + l16;
        float bv = bias ? bf2f(bias[gc]) : 0.f;
#pragma unroll
        for (int i = 0; i < 4; i++) {
            int grb = m0 + wm + i * 16 + quad * 4;
#pragma unroll
            for (int r = 0; r < 4; r++) {
                int gr = grb + r;
                if (gr < M) {
                    float v = acc[i][j][r] + bv;
                    if (act) v = v > 0.f ? v : 0.01f * v;
                    C[(size_t)gr * ldc + gc] = f2bf(v);
                }
            }
        }
    }
}

// ---------- weight prep (flag-aware source dtype, bf16 out) ----------
__global__ void t_cvt(const void* __restrict__ in, unsigned short* __restrict__ out,
                      int R, int C, const int* __restrict__ dflag) {
    int f32 = *dflag;
    int i = blockIdx.x * 256 + threadIdx.x;
    if (i < R * C) {
        int r = i / C, c = i % C;
        out[(size_t)c * R + r] = f2bf(ldf(in, i, f32));
    }
}

// Bt for RGCN layer: out[256][768], out[n][k] = k<256 ? root[k][n] : rel[(k-256)*H+n]
__global__ void build_bt(const void* __restrict__ root, const void* __restrict__ rel,
                         unsigned short* __restrict__ out, int H,
                         const int* __restrict__ dflag) {
    int f32 = *dflag;
    int i = blockIdx.x * 256 + threadIdx.x;
    int K3 = 3 * H;
    if (i < H * K3) {
        int k = i % K3;
        int n = i / K3;
        float v = (k < H) ? ldf(root, (size_t)k * H + n, f32)
                          : ldf(rel, (size_t)(k - H) * H + n, f32);
        out[i] = f2bf(v);
    }
}

__global__ void cvt_vec(const void* __restrict__ in, unsigned short* __restrict__ out,
                        int n, const int* __restrict__ dflag) {
    int f32 = *dflag;
    int i = blockIdx.x * 256 + threadIdx.x;
    if (i < n) out[i] = f2bf(ldf(in, i, f32));
}

// ---------- CSR build ----------
__global__ void k_hist(const int* __restrict__ ei, const int* __restrict__ et,
                       int* cnt2, int N, int E) {
    int e = blockIdx.x * 256 + threadIdx.x;
    if (e < E) {
        int dst = ei[E + e];
        int t = et[e] & 1;
        if ((unsigned)dst < (unsigned)N) atomicAdd(&cnt2[t * N + dst], 1);
    }
}

__global__ void k_scan1(const int* __restrict__ cnt2, int* rowptr, int* bsum, int N) {
    __shared__ int sh[256];
    int t = threadIdx.x;
    int base = blockIdx.x * 1024 + t * 4;
    int v[4];
    int s = 0;
#pragma unroll
    for (int k = 0; k < 4; k++) {
        int idx = base + k;
        v[k] = (idx < N) ? (cnt2[idx] + cnt2[N + idx]) : 0;
        s += v[k];
    }
    sh[t] = s;
    __syncthreads();
    for (int off = 1; off < 256; off <<= 1) {
        int x = 0;
        if (t >= off) x = sh[t - off];
        __syncthreads();
        if (t >= off) sh[t] += x;
        __syncthreads();
    }
    int excl = sh[t] - s;
    int run = excl;
#pragma unroll
    for (int k = 0; k < 4; k++) {
        int idx = base + k;
        if (idx < N) rowptr[idx] = run;
        run += v[k];
    }
    if (t == 255) bsum[blockIdx.x] = sh[255];
}

__global__ void k_scan2(const int* __restrict__ bsum, int* bofs, int nb) {
    int t = threadIdx.x;  // 64
    int v = (t < nb) ? bsum[t] : 0;
    int orig = v;
    for (int off = 1; off < 64; off <<= 1) {
        int x = __shfl_up(v, off);
        if (t >= off) v += x;
    }
    if (t < nb) bofs[t] = v - orig;
}

__global__ void k_scan3(int* rowptr, const int* __restrict__ bofs, int N) {
    int i = blockIdx.x * 256 + threadIdx.x;
    if (i < N) rowptr[i] += bofs[i >> 10];
}

__global__ void k_fill(const int* __restrict__ ei, const int* __restrict__ et,
                       const int* __restrict__ rowptr, int* cursor, int* sorted,
                       int N, int E) {
    int e = blockIdx.x * 256 + threadIdx.x;
    if (e < E) {
        int src = ei[e];
        int dst = ei[E + e];
        int t = et[e] & 1;
        if ((unsigned)dst < (unsigned)N && (unsigned)src < (unsigned)N) {
            int pos = rowptr[dst] + atomicAdd(&cursor[dst], 1);
            sorted[pos] = src | (t << 24);
        }
    }
}

// ---------- aggregation: one wave per node, mean of x[src] per relation ----------
__global__ __launch_bounds__(256) void k_agg(
    const unsigned short* __restrict__ x,
    unsigned short* __restrict__ m0,
    unsigned short* __restrict__ m1,
    int N,
    const int* __restrict__ rowptr, const int* __restrict__ cnt2,
    const int* __restrict__ sorted)
{
    int wave = threadIdx.x >> 6;
    int lane = threadIdx.x & 63;
    int node = blockIdx.x * 4 + wave;
    if (node >= N) return;

    int start = rowptr[node];
    int c0 = cnt2[node], c1 = cnt2[N + node];
    int deg = c0 + c1;

    float a0[4] = {0.f, 0.f, 0.f, 0.f};
    float a1[4] = {0.f, 0.f, 0.f, 0.f};

    for (int b = 0; b < deg; b += 64) {
        int p = 0;
        if (b + lane < deg) p = sorted[start + b + lane];
        int cnt = deg - b; if (cnt > 64) cnt = 64;
        for (int j = 0; j < cnt; j++) {
            int q = __shfl(p, j);
            int src = q & 0xFFFFFF;
            if (src >= N) src = 0;
            const uint2* pr = (const uint2*)(x + (size_t)src * 256) + lane;
            uint2 raw = *pr;
            float v0 = bf2f((unsigned short)(raw.x & 0xFFFFu));
            float v1 = bf2f((unsigned short)(raw.x >> 16));
            float v2 = bf2f((unsigned short)(raw.y & 0xFFFFu));
            float v3 = bf2f((unsigned short)(raw.y >> 16));
            if ((q >> 24) == 0) { a0[0] += v0; a0[1] += v1; a0[2] += v2; a0[3] += v3; }
            else               { a1[0] += v0; a1[1] += v1; a1[2] += v2; a1[3] += v3; }
        }
    }
    float i0 = c0 > 0 ? 1.f / (float)c0 : 0.f;
    float i1 = c1 > 0 ? 1.f / (float)c1 : 0.f;
    uint2 o0, o1;
    o0.x = (unsigned int)f2bf(a0[0] * i0) | ((unsigned int)f2bf(a0[1] * i0) << 16);
    o0.y = (unsigned int)f2bf(a0[2] * i0) | ((unsigned int)f2bf(a0[3] * i0) << 16);
    o1.x = (unsigned int)f2bf(a1[0] * i1) | ((unsigned int)f2bf(a1[1] * i1) << 16);
    o1.y = (unsigned int)f2bf(a1[2] * i1) | ((unsigned int)f2bf(a1[3] * i1) << 16);
    *((uint2*)(m0 + (size_t)node * 256) + lane) = o0;
    *((uint2*)(m1 + (size_t)node * 256) + lane) = o1;
}

// ---------- small-K encode (num_prop K=5 -> cols 128..191, cat K=3 -> 192..255) ----------
__global__ void k_small(const void* __restrict__ num, const void* __restrict__ cat,
                        const void* __restrict__ Wn, const void* __restrict__ bnp,
                        const void* __restrict__ Wc, const void* __restrict__ bcp,
                        unsigned short* __restrict__ xcat, int N,
                        const int* __restrict__ dflag)
{
    int f32 = *dflag;
    __shared__ float wn[320], wc[192], bns[64], bcs[64];
    int t = threadIdx.x;
    for (int i = t; i < 320; i += 256) wn[i] = ldf(Wn, i, f32);
    for (int i = t; i < 192; i += 256) wc[i] = ldf(Wc, i, f32);
    if (t < 64) { bns[t] = ldf(bnp, t, f32); bcs[t] = ldf(bcp, t, f32); }
    __syncthreads();

    int node = blockIdx.x * 128 + (t >> 1);
    int half = t & 1;
    if (node >= N) return;
    if (half == 0) {
        float in5[5];
#pragma unroll
        for (int i = 0; i < 5; i++) in5[i] = ldf(num, (size_t)node * 5 + i, f32);
        unsigned short* orow = xcat + (size_t)node * 256 + 128;
#pragma unroll 4
        for (int c = 0; c < 64; c++) {
            float v = bns[c];
#pragma unroll
            for (int i = 0; i < 5; i++) v += in5[i] * wn[i * 64 + c];
            v = v > 0.f ? v : 0.01f * v;
            orow[c] = f2bf(v);
        }
    } else {
        float in3[3];
#pragma unroll
        for (int i = 0; i < 3; i++) in3[i] = ldf(cat, (size_t)node * 3 + i, f32);
        unsigned short* orow = xcat + (size_t)node * 256 + 192;
#pragma unroll 4
        for (int c = 0; c < 64; c++) {
            float v = bcs[c];
#pragma unroll
            for (int i = 0; i < 3; i++) v += in3[i] * wc[i * 64 + c];
            v = v > 0.f ? v : 0.01f * v;
            orow[c] = f2bf(v);
        }
    }
}

// ---------- final projection: out[N,2] = z[N,256] @ Wo2[256,2] + bo2 ----------
__global__ __launch_bounds__(256) void k_final(
    const unsigned short* __restrict__ z,
    const void* __restrict__ Wo2, const void* __restrict__ bo2,
    void* __restrict__ out, int N, const int* __restrict__ dflag)
{
    int f32 = *dflag;
    __shared__ float w[512];
    int t = threadIdx.x;
    for (int i = t; i < 512; i += 256) w[i] = ldf(Wo2, i, f32);
    __syncthreads();
    int wave = t >> 6, lane = t & 63;
    int node = blockIdx.x * 4 + wave;
    if (node >= N) return;
    uint2 raw = *((const uint2*)(z + (size_t)node * 256) + lane);
    float v0 = bf2f((unsigned short)(raw.x & 0xFFFFu));
    float v1 = bf2f((unsigned short)(raw.x >> 16));
    float v2 = bf2f((unsigned short)(raw.y & 0xFFFFu));
    float v3 = bf2f((unsigned short)(raw.y >> 16));
    int k0 = lane * 4;
    float s0 = v0 * w[k0 * 2]     + v1 * w[(k0 + 1) * 2]     + v2 * w[(k0 + 2) * 2]     + v3 * w[(k0 + 3) * 2];
    float s1 = v0 * w[k0 * 2 + 1] + v1 * w[(k0 + 1) * 2 + 1] + v2 * w[(k0 + 2) * 2 + 1] + v3 * w[(k0 + 3) * 2 + 1];
    for (int off = 32; off; off >>= 1) {
        s0 += __shfl_xor(s0, off);
        s1 += __shfl_xor(s1, off);
    }
    if (lane == 0) {
        s0 += ldf(bo2, 0, f32);
        s1 += ldf(bo2, 1, f32);
        if (f32) {
            ((float*)out)[(size_t)node * 2]     = s0;
            ((float*)out)[(size_t)node * 2 + 1] = s1;
        } else {
            ((unsigned short*)out)[(size_t)node * 2]     = f2bf(s0);
            ((unsigned short*)out)[(size_t)node * 2 + 1] = f2bf(s1);
        }
    }
}

// ---------------------------------------------------------------------------
extern "C" void kernel_launch(void* const* d_in, const int* in_sizes, int n_in,
                              void* d_out, int out_size, void* d_ws, size_t ws_size,
                              hipStream_t stream)
{
    (void)n_in; (void)out_size; (void)ws_size;
    const void* des   = d_in[0];
    const void* tweet = d_in[1];
    const void* nump  = d_in[2];
    const void* catp  = d_in[3];
    const int*  ei    = (const int*)d_in[4];
    const int*  et    = (const int*)d_in[5];
    const void* Wd  = d_in[6];
    const void* bd  = d_in[7];
    const void* Wt  = d_in[8];
    const void* bt  = d_in[9];
    const void* Wn  = d_in[10];
    const void* bn  = d_in[11];
    const void* Wc  = d_in[12];
    const void* bc  = d_in[13];
    const void* Wi  = d_in[14];
    const void* bi  = d_in[15];
    const void* rel1  = d_in[16];
    const void* root1 = d_in[17];
    const void* bias1 = d_in[18];
    const void* rel2  = d_in[19];
    const void* root2 = d_in[20];
    const void* bias2 = d_in[21];
    const void* Wo1 = d_in[22];
    const void* bo1 = d_in[23];
    const void* Wo2 = d_in[24];
    const void* bo2 = d_in[25];

    const int N = in_sizes[0] / 768;
    const int E = in_sizes[5];

    char* ws = (char*)d_ws;
    size_t off = 0;
    auto alloc = [&](size_t bytes) -> char* {
        char* p = ws + off;
        off += (bytes + 255) & ~(size_t)255;
        return p;
    };
    unsigned short* B0 = (unsigned short*)alloc((size_t)N * 256 * 2);  // xcat / y1 / z
    unsigned short* B1 = (unsigned short*)alloc((size_t)N * 256 * 2);  // x / y2
    unsigned short* B2 = (unsigned short*)alloc((size_t)N * 256 * 2);  // m0
    unsigned short* B3 = (unsigned short*)alloc((size_t)N * 256 * 2);  // m1
    unsigned short* WdT  = (unsigned short*)alloc(64 * 768 * 2);
    unsigned short* WtT  = (unsigned short*)alloc(64 * 768 * 2);
    unsigned short* WiT  = (unsigned short*)alloc(256 * 256 * 2);
    unsigned short* Wo1T = (unsigned short*)alloc(256 * 256 * 2);
    unsigned short* BT1  = (unsigned short*)alloc(256 * 768 * 2);
    unsigned short* BT2  = (unsigned short*)alloc(256 * 768 * 2);
    unsigned short* bias_bf = (unsigned short*)alloc(1152 * 2);
    unsigned short* bd_bf = bias_bf;          // 64
    unsigned short* bt_bf = bias_bf + 64;     // 64
    unsigned short* bi_bf = bias_bf + 128;    // 256
    unsigned short* b1_bf = bias_bf + 384;    // 256
    unsigned short* b2_bf = bias_bf + 640;    // 256
    unsigned short* bo1_bf = bias_bf + 896;   // 256
    int* dflag  = (int*)alloc(4);
    int* cnt2   = (int*)alloc((size_t)2 * N * 4);
    int* rowptr = (int*)alloc((size_t)(N + 1) * 4);
    int* cursor = (int*)alloc((size_t)N * 4);
    int* bsum   = (int*)alloc(64 * 4);
    int* bofs   = (int*)alloc(64 * 4);
    int* sorted = (int*)alloc((size_t)E * 4);

    // zero CSR region (cnt2 .. sorted inclusive)
    size_t zlen = (size_t)(((char*)sorted + (size_t)E * 4) - (char*)cnt2);
    hipMemsetAsync(cnt2, 0, zlen, stream);

    // dtype detect (must precede all flag-readers)
    k_detect<<<1, 256, 0, stream>>>((const unsigned short*)des, dflag);

    // weight prep (flag-aware src dtype)
    t_cvt<<<(768 * 64 + 255) / 256, 256, 0, stream>>>(Wd, WdT, 768, 64, dflag);
    t_cvt<<<(768 * 64 + 255) / 256, 256, 0, stream>>>(Wt, WtT, 768, 64, dflag);
    t_cvt<<<(256 * 256 + 255) / 256, 256, 0, stream>>>(Wi, WiT, 256, 256, dflag);
    t_cvt<<<(256 * 256 + 255) / 256, 256, 0, stream>>>(Wo1, Wo1T, 256, 256, dflag);
    build_bt<<<(256 * 768 + 255) / 256, 256, 0, stream>>>(root1, rel1, BT1, 256, dflag);
    build_bt<<<(256 * 768 + 255) / 256, 256, 0, stream>>>(root2, rel2, BT2, 256, dflag);
    cvt_vec<<<1, 256, 0, stream>>>(bd, bd_bf, 64, dflag);
    cvt_vec<<<1, 256, 0, stream>>>(bt, bt_bf, 64, dflag);
    cvt_vec<<<1, 256, 0, stream>>>(bi, bi_bf, 256, dflag);
    cvt_vec<<<1, 256, 0, stream>>>(bias1, b1_bf, 256, dflag);
    cvt_vec<<<1, 256, 0, stream>>>(bias2, b2_bf, 256, dflag);
    cvt_vec<<<1, 256, 0, stream>>>(bo1, bo1_bf, 256, dflag);

    // CSR build
    int eb = (E + 255) / 256;
    k_hist<<<eb, 256, 0, stream>>>(ei, et, cnt2, N, E);
    int nb = (N + 1023) / 1024;
    k_scan1<<<nb, 256, 0, stream>>>(cnt2, rowptr, bsum, N);
    k_scan2<<<1, 64, 0, stream>>>(bsum, bofs, nb);
    k_scan3<<<(N + 255) / 256, 256, 0, stream>>>(rowptr, bofs, N);
    k_fill<<<eb, 256, 0, stream>>>(ei, et, rowptr, cursor, sorted, N, E);

    // feature encode -> B0 (xcat) [N,256]
    dim3 g64((N + 127) / 128, 1);
    gemm_nt<64><<<g64, 256, 0, stream>>>(des, des, des, 0, 256, 512, 768, WdT, 768,
                                         B0, 256, bd_bf, N, 768, 1, dflag);
    gemm_nt<64><<<g64, 256, 0, stream>>>(tweet, tweet, tweet, 0, 256, 512, 768, WtT, 768,
                                         B0 + 64, 256, bt_bf, N, 768, 1, dflag);
    k_small<<<(N + 127) / 128, 256, 0, stream>>>(nump, catp, Wn, bn, Wc, bc, B0, N, dflag);

    // x = lrelu(xcat @ Wi + bi) -> B1
    dim3 g128((N + 127) / 128, 2);
    gemm_nt<128><<<g128, 256, 0, stream>>>(B0, B0, B0, 0, 0, 0, 256, WiT, 256,
                                           B1, 256, bi_bf, N, 256, 1, nullptr);

    // RGCN layer 1: aggregate x (B1) -> B2, B3; fused K=768 GEMM -> B0
    int ab = (N + 3) / 4;
    k_agg<<<ab, 256, 0, stream>>>(B1, B2, B3, N, rowptr, cnt2, sorted);
    gemm_nt<128><<<g128, 256, 0, stream>>>(B1, B2, B3, 0, 0, 0, 256, BT1, 768,
                                           B0, 256, b1_bf, N, 768, 0, nullptr);

    // RGCN layer 2: aggregate y1 (B0) -> B2, B3; GEMM -> B1
    k_agg<<<ab, 256, 0, stream>>>(B0, B2, B3, N, rowptr, cnt2, sorted);
    gemm_nt<128><<<g128, 256, 0, stream>>>(B0, B2, B3, 0, 0, 0, 256, BT2, 768,
                                           B1, 256, b2_bf, N, 768, 0, nullptr);

    // z = lrelu(y2 @ Wo1 + bo1) -> B0
    gemm_nt<128><<<g128, 256, 0, stream>>>(B1, B1, B1, 0, 0, 0, 256, Wo1T, 256,
                                           B0, 256, bo1_bf, N, 256, 1, nullptr);

    // out = z @ Wo2 + bo2
    k_final<<<ab, 256, 0, stream>>>(B0, Wo2, bo2, d_out, N, dflag);
}

// Round 4
// 819.615 us; speedup vs baseline: 1.0538x; 1.0538x over previous
//
#include <hip/hip_runtime.h>
#include <stdint.h>

// ---------- bf16 helpers (raw ushort storage) ----------
__device__ __forceinline__ float bf2f(unsigned short h) {
    union { unsigned int u; float f; } x;
    x.u = ((unsigned int)h) << 16;
    return x.f;
}
__device__ __forceinline__ unsigned short f2bf(float f) {
    union { float f; unsigned int u; } x;
    x.f = f;
    unsigned int u = x.u;
    unsigned int r = (u + 0x7FFFu + ((u >> 16) & 1u)) >> 16;  // RNE
    return (unsigned short)r;
}
__device__ __forceinline__ float ldf(const void* p, size_t i, int f32) {
    return f32 ? ((const float*)p)[i] : bf2f(((const unsigned short*)p)[i]);
}

typedef __attribute__((ext_vector_type(8))) short short8;
typedef __attribute__((ext_vector_type(4))) float floatx4;

// ---------- dtype detect: fp32 reinterpreted as bf16 shows huge exponents ----------
__global__ void k_detect(const unsigned short* __restrict__ p, int* flag) {
    __shared__ int cnt;
    if (threadIdx.x == 0) cnt = 0;
    __syncthreads();
    int c = 0;
    for (int i = threadIdx.x; i < 4096; i += 256) {
        unsigned e = (p[i] >> 7) & 0xFFu;
        if (e >= 0xC0u) c++;
    }
    atomicAdd(&cnt, c);
    __syncthreads();
    if (threadIdx.x == 0) *flag = (cnt > 32) ? 1 : 0;
}

// ---------------------------------------------------------------------------
// Tiled MFMA GEMM. TWO=true: blockIdx.y selects a second full input set
// (used to fuse the des/tweet encode GEMMs into one launch).
// A parts cover k in [256p, 256p+256) at element offsets o0/o1/o2.
// ---------------------------------------------------------------------------
template <int BN, bool TWO>
__global__ __launch_bounds__(256) void gemm_nt(
    const void* __restrict__ A0, const void* __restrict__ A1,
    const void* __restrict__ A2, int o0, int o1, int o2, int lda,
    const unsigned short* __restrict__ Bt, int ldb,
    unsigned short* __restrict__ C, int ldc,
    const unsigned short* __restrict__ bias,
    int M, int K, int act, const int* __restrict__ dflag,
    const void* Ab = nullptr, const unsigned short* Btb = nullptr,
    unsigned short* Cb = nullptr, const unsigned short* biasb = nullptr)
{
    constexpr int BM = 128, BK = 64;
    constexpr int NJ = (BN == 128) ? 4 : 2;
    const int af32 = dflag ? *dflag : 0;
    const int tid  = threadIdx.x;
    const int wave = tid >> 6;
    const int lane = tid & 63;
    const int quad = lane >> 4;
    const int l16  = lane & 15;
    const int m0   = blockIdx.x * BM;
    const int wm   = (wave & 1) * 64;
    const int wn   = (wave >> 1) * (BN / 2);
    int n0;
    const unsigned short* BtS;
    unsigned short* CS;
    const unsigned short* biasS;
    const void *A0S, *A1S, *A2S;
    if (TWO && blockIdx.y == 1) {
        n0 = 0; BtS = Btb; CS = Cb; biasS = biasb;
        A0S = Ab; A1S = Ab; A2S = Ab;
    } else {
        n0 = TWO ? 0 : blockIdx.y * BN;
        BtS = Bt; CS = C; biasS = bias;
        A0S = A0; A1S = A1; A2S = A2;
    }

    __shared__ short8 As[8 * (BM + 2)];
    __shared__ short8 Bs[8 * (BN + 2)];

    floatx4 acc[4][NJ];
#pragma unroll
    for (int i = 0; i < 4; i++)
#pragma unroll
        for (int j = 0; j < NJ; j++) acc[i][j] = (floatx4){0.f, 0.f, 0.f, 0.f};

    for (int kt = 0; kt < K; kt += BK) {
        const void* Ap = (kt < 256) ? A0S : (kt < 512) ? A1S : A2S;
        const int Ao = (kt < 256) ? o0 : (kt < 512) ? o1 : o2;
        const int ko = kt & 255;
#pragma unroll
        for (int c = 0; c < 4; c++) {
            int lin = c * 256 + tid;
            int row = lin >> 3, kq = lin & 7;
            int gr = m0 + row; if (gr > M - 1) gr = M - 1;
            size_t eoff = (size_t)gr * lda + Ao + ko + kq * 8;
            short8 v;
            if (af32) {
                const float4* pf = (const float4*)((const float*)Ap + eoff);
                float4 f0 = pf[0];
                float4 f1 = pf[1];
                v[0] = (short)f2bf(f0.x); v[1] = (short)f2bf(f0.y);
                v[2] = (short)f2bf(f0.z); v[3] = (short)f2bf(f0.w);
                v[4] = (short)f2bf(f1.x); v[5] = (short)f2bf(f1.y);
                v[6] = (short)f2bf(f1.z); v[7] = (short)f2bf(f1.w);
            } else {
                v = *(const short8*)((const unsigned short*)Ap + eoff);
            }
            As[kq * (BM + 2) + row] = v;
        }
#pragma unroll
        for (int c = 0; c < (BN * 8) / 256; c++) {
            int lin = c * 256 + tid;
            int n = lin >> 3, kq = lin & 7;
            short8 v = *(const short8*)(BtS + (size_t)(n0 + n) * ldb + kt + kq * 8);
            Bs[kq * (BN + 2) + n] = v;
        }
        __syncthreads();
#pragma unroll
        for (int s = 0; s < 2; s++) {
            short8 af[4], bfr[NJ];
#pragma unroll
            for (int i = 0; i < 4; i++)
                af[i] = As[(s * 4 + quad) * (BM + 2) + wm + i * 16 + l16];
#pragma unroll
            for (int j = 0; j < NJ; j++)
                bfr[j] = Bs[(s * 4 + quad) * (BN + 2) + wn + j * 16 + l16];
#pragma unroll
            for (int i = 0; i < 4; i++)
#pragma unroll
                for (int j = 0; j < NJ; j++)
                    acc[i][j] = __builtin_amdgcn_mfma_f32_16x16x32_bf16(
                        af[i], bfr[j], acc[i][j], 0, 0, 0);
        }
        __syncthreads();
    }

    // epilogue: C/D layout col = lane&15, row = quad*4 + reg  [m89-verified]
#pragma unroll
    for (int j = 0; j < NJ; j++) {
        int gc = n0 + wn + j * 16 + l16;
        float bv = biasS ? bf2f(biasS[gc]) : 0.f;
#pragma unroll
        for (int i = 0; i < 4; i++) {
            int grb = m0 + wm + i * 16 + quad * 4;
#pragma unroll
            for (int r = 0; r < 4; r++) {
                int gr = grb + r;
                if (gr < M) {
                    float v = acc[i][j][r] + bv;
                    if (act) v = v > 0.f ? v : 0.01f * v;
                    CS[(size_t)gr * ldc + gc] = f2bf(v);
                }
            }
        }
    }
}

// ---------- weight prep ----------
__global__ void t_cvt(const void* __restrict__ in, unsigned short* __restrict__ out,
                      int R, int C, const int* __restrict__ dflag) {
    int f32 = *dflag;
    int i = blockIdx.x * 256 + threadIdx.x;
    if (i < R * C) {
        int r = i / C, c = i % C;
        out[(size_t)c * R + r] = f2bf(ldf(in, i, f32));
    }
}

__global__ void build_bt(const void* __restrict__ root, const void* __restrict__ rel,
                         unsigned short* __restrict__ out, int H,
                         const int* __restrict__ dflag) {
    int f32 = *dflag;
    int i = blockIdx.x * 256 + threadIdx.x;
    int K3 = 3 * H;
    if (i < H * K3) {
        int k = i % K3;
        int n = i / K3;
        float v = (k < H) ? ldf(root, (size_t)k * H + n, f32)
                          : ldf(rel, (size_t)(k - H) * H + n, f32);
        out[i] = f2bf(v);
    }
}

// all six bias vectors in one launch; layout: [bd 64][bt 64][bi 256][b1 256][b2 256][bo1 256]
__global__ void k_biases(const void* bd, const void* bt, const void* bi,
                         const void* b1, const void* b2, const void* bo1,
                         unsigned short* __restrict__ out, const int* __restrict__ dflag) {
    int f32 = *dflag;
    for (int idx = threadIdx.x; idx < 1152; idx += 256) {
        const void* p; int off;
        if (idx < 64)       { p = bd;  off = idx; }
        else if (idx < 128) { p = bt;  off = idx - 64; }
        else if (idx < 384) { p = bi;  off = idx - 128; }
        else if (idx < 640) { p = b1;  off = idx - 384; }
        else if (idx < 896) { p = b2;  off = idx - 640; }
        else                { p = bo1; off = idx - 896; }
        out[idx] = f2bf(ldf(p, off, f32));
    }
}

// ---------- CSR build ----------
__global__ void k_hist(const int* __restrict__ ei, const int* __restrict__ et,
                       int* cnt2, int N, int E) {
    int e = blockIdx.x * 256 + threadIdx.x;
    if (e < E) {
        int dst = ei[E + e];
        int t = et[e] & 1;
        if ((unsigned)dst < (unsigned)N) atomicAdd(&cnt2[t * N + dst], 1);
    }
}

__global__ void k_scan1(const int* __restrict__ cnt2, int* rowptr, int* bsum, int N) {
    __shared__ int sh[256];
    int t = threadIdx.x;
    int base = blockIdx.x * 1024 + t * 4;
    int v[4];
    int s = 0;
#pragma unroll
    for (int k = 0; k < 4; k++) {
        int idx = base + k;
        v[k] = (idx < N) ? (cnt2[idx] + cnt2[N + idx]) : 0;
        s += v[k];
    }
    sh[t] = s;
    __syncthreads();
    for (int off = 1; off < 256; off <<= 1) {
        int x = 0;
        if (t >= off) x = sh[t - off];
        __syncthreads();
        if (t >= off) sh[t] += x;
        __syncthreads();
    }
    int excl = sh[t] - s;
    int run = excl;
#pragma unroll
    for (int k = 0; k < 4; k++) {
        int idx = base + k;
        if (idx < N) rowptr[idx] = run;
        run += v[k];
    }
    if (t == 255) bsum[blockIdx.x] = sh[255];
}

__global__ void k_scan2(const int* __restrict__ bsum, int* bofs, int nb) {
    int t = threadIdx.x;  // 64
    int v = (t < nb) ? bsum[t] : 0;
    int orig = v;
    for (int off = 1; off < 64; off <<= 1) {
        int x = __shfl_up(v, off);
        if (t >= off) v += x;
    }
    if (t < nb) bofs[t] = v - orig;
}

__global__ void k_scan3(int* rowptr, const int* __restrict__ bofs, int N) {
    int i = blockIdx.x * 256 + threadIdx.x;
    if (i < N) rowptr[i] += bofs[i >> 10];
}

__global__ void k_fill(const int* __restrict__ ei, const int* __restrict__ et,
                       const int* __restrict__ rowptr, int* cursor, int* sorted,
                       int N, int E) {
    int e = blockIdx.x * 256 + threadIdx.x;
    if (e < E) {
        int src = ei[e];
        int dst = ei[E + e];
        int t = et[e] & 1;
        if ((unsigned)dst < (unsigned)N && (unsigned)src < (unsigned)N) {
            int pos = rowptr[dst] + atomicAdd(&cursor[dst], 1);
            sorted[pos] = src | (t << 24);
        }
    }
}

// ---------- aggregation v2: one wave per node, 2 edges per iteration ----------
// lanes 0-31 handle even edges, 32-63 odd edges; 16 B (8 cols) per lane.
// Cross-half shfl_xor(32) combine at the end; half 0 stores m0, half 1 m1.
__global__ __launch_bounds__(256) void k_agg(
    const unsigned short* __restrict__ x,
    unsigned short* __restrict__ m0,
    unsigned short* __restrict__ m1,
    int N,
    const int* __restrict__ rowptr, const int* __restrict__ cnt2,
    const int* __restrict__ sorted)
{
    int wave = threadIdx.x >> 6;
    int lane = threadIdx.x & 63;
    int half = lane >> 5;
    int l32  = lane & 31;
    int node = blockIdx.x * 4 + wave;
    if (node >= N) return;

    int start = rowptr[node];
    int c0 = cnt2[node], c1 = cnt2[N + node];
    int deg = c0 + c1;

    float a0[8] = {0,0,0,0,0,0,0,0};
    float a1[8] = {0,0,0,0,0,0,0,0};

    for (int b = 0; b < deg; b += 64) {
        int rem = deg - b; if (rem > 64) rem = 64;
        int p = 0;
        if (lane < rem) p = sorted[start + b + lane];
        int iters = (rem + 1) >> 1;
        for (int t = 0; t < iters; t += 2) {
            int e0 = 2 * t + half;
            int e1 = e0 + 2;
            int q0 = __shfl(p, e0 < 64 ? e0 : 63);
            int q1 = __shfl(p, e1 < 64 ? e1 : 63);
            bool v0ok = e0 < rem;
            bool v1ok = e1 < rem;
            int s0 = q0 & 0xFFFFFF; if (s0 >= N) s0 = 0;
            int s1 = q1 & 0xFFFFFF; if (s1 >= N) s1 = 0;
            uint4 r0 = *((const uint4*)(x + (size_t)s0 * 256) + l32);
            uint4 r1 = *((const uint4*)(x + (size_t)s1 * 256) + l32);
            if (v0ok) {
                float f[8];
                f[0] = bf2f((unsigned short)(r0.x & 0xFFFFu)); f[1] = bf2f((unsigned short)(r0.x >> 16));
                f[2] = bf2f((unsigned short)(r0.y & 0xFFFFu)); f[3] = bf2f((unsigned short)(r0.y >> 16));
                f[4] = bf2f((unsigned short)(r0.z & 0xFFFFu)); f[5] = bf2f((unsigned short)(r0.z >> 16));
                f[6] = bf2f((unsigned short)(r0.w & 0xFFFFu)); f[7] = bf2f((unsigned short)(r0.w >> 16));
                if ((q0 >> 24) & 1) {
#pragma unroll
                    for (int k = 0; k < 8; k++) a1[k] += f[k];
                } else {
#pragma unroll
                    for (int k = 0; k < 8; k++) a0[k] += f[k];
                }
            }
            if (v1ok) {
                float f[8];
                f[0] = bf2f((unsigned short)(r1.x & 0xFFFFu)); f[1] = bf2f((unsigned short)(r1.x >> 16));
                f[2] = bf2f((unsigned short)(r1.y & 0xFFFFu)); f[3] = bf2f((unsigned short)(r1.y >> 16));
                f[4] = bf2f((unsigned short)(r1.z & 0xFFFFu)); f[5] = bf2f((unsigned short)(r1.z >> 16));
                f[6] = bf2f((unsigned short)(r1.w & 0xFFFFu)); f[7] = bf2f((unsigned short)(r1.w >> 16));
                if ((q1 >> 24) & 1) {
#pragma unroll
                    for (int k = 0; k < 8; k++) a1[k] += f[k];
                } else {
#pragma unroll
                    for (int k = 0; k < 8; k++) a0[k] += f[k];
                }
            }
        }
    }
    // cross-half combine (even-edge half + odd-edge half)
#pragma unroll
    for (int k = 0; k < 8; k++) {
        a0[k] += __shfl_xor(a0[k], 32);
        a1[k] += __shfl_xor(a1[k], 32);
    }
    float i0 = c0 > 0 ? 1.f / (float)c0 : 0.f;
    float i1 = c1 > 0 ? 1.f / (float)c1 : 0.f;
    uint4 o;
    if (half == 0) {
        o.x = (unsigned)f2bf(a0[0] * i0) | ((unsigned)f2bf(a0[1] * i0) << 16);
        o.y = (unsigned)f2bf(a0[2] * i0) | ((unsigned)f2bf(a0[3] * i0) << 16);
        o.z = (unsigned)f2bf(a0[4] * i0) | ((unsigned)f2bf(a0[5] * i0) << 16);
        o.w = (unsigned)f2bf(a0[6] * i0) | ((unsigned)f2bf(a0[7] * i0) << 16);
        *((uint4*)(m0 + (size_t)node * 256) + l32) = o;
    } else {
        o.x = (unsigned)f2bf(a1[0] * i1) | ((unsigned)f2bf(a1[1] * i1) << 16);
        o.y = (unsigned)f2bf(a1[2] * i1) | ((unsigned)f2bf(a1[3] * i1) << 16);
        o.z = (unsigned)f2bf(a1[4] * i1) | ((unsigned)f2bf(a1[5] * i1) << 16);
        o.w = (unsigned)f2bf(a1[6] * i1) | ((unsigned)f2bf(a1[7] * i1) << 16);
        *((uint4*)(m1 + (size_t)node * 256) + l32) = o;
    }
}

// ---------- small-K encode (num_prop K=5 -> cols 128..191, cat K=3 -> 192..255) ----------
__global__ void k_small(const void* __restrict__ num, const void* __restrict__ cat,
                        const void* __restrict__ Wn, const void* __restrict__ bnp,
                        const void* __restrict__ Wc, const void* __restrict__ bcp,
                        unsigned short* __restrict__ xcat, int N,
                        const int* __restrict__ dflag)
{
    int f32 = *dflag;
    __shared__ float wn[320], wc[192], bns[64], bcs[64];
    int t = threadIdx.x;
    for (int i = t; i < 320; i += 256) wn[i] = ldf(Wn, i, f32);
    for (int i = t; i < 192; i += 256) wc[i] = ldf(Wc, i, f32);
    if (t < 64) { bns[t] = ldf(bnp, t, f32); bcs[t] = ldf(bcp, t, f32); }
    __syncthreads();

    int node = blockIdx.x * 128 + (t >> 1);
    int half = t & 1;
    if (node >= N) return;
    if (half == 0) {
        float in5[5];
#pragma unroll
        for (int i = 0; i < 5; i++) in5[i] = ldf(num, (size_t)node * 5 + i, f32);
        unsigned short* orow = xcat + (size_t)node * 256 + 128;
#pragma unroll 4
        for (int c = 0; c < 64; c++) {
            float v = bns[c];
#pragma unroll
            for (int i = 0; i < 5; i++) v += in5[i] * wn[i * 64 + c];
            v = v > 0.f ? v : 0.01f * v;
            orow[c] = f2bf(v);
        }
    } else {
        float in3[3];
#pragma unroll
        for (int i = 0; i < 3; i++) in3[i] = ldf(cat, (size_t)node * 3 + i, f32);
        unsigned short* orow = xcat + (size_t)node * 256 + 192;
#pragma unroll 4
        for (int c = 0; c < 64; c++) {
            float v = bcs[c];
#pragma unroll
            for (int i = 0; i < 3; i++) v += in3[i] * wc[i * 64 + c];
            v = v > 0.f ? v : 0.01f * v;
            orow[c] = f2bf(v);
        }
    }
}

// ---------- final projection: out[N,2] = z[N,256] @ Wo2[256,2] + bo2 ----------
__global__ __launch_bounds__(256) void k_final(
    const unsigned short* __restrict__ z,
    const void* __restrict__ Wo2, const void* __restrict__ bo2,
    void* __restrict__ out, int N, const int* __restrict__ dflag)
{
    int f32 = *dflag;
    __shared__ float w[512];
    int t = threadIdx.x;
    for (int i = t; i < 512; i += 256) w[i] = ldf(Wo2, i, f32);
    __syncthreads();
    int wave = t >> 6, lane = t & 63;
    int node = blockIdx.x * 4 + wave;
    if (node >= N) return;
    uint2 raw = *((const uint2*)(z + (size_t)node * 256) + lane);
    float v0 = bf2f((unsigned short)(raw.x & 0xFFFFu));
    float v1 = bf2f((unsigned short)(raw.x >> 16));
    float v2 = bf2f((unsigned short)(raw.y & 0xFFFFu));
    float v3 = bf2f((unsigned short)(raw.y >> 16));
    int k0 = lane * 4;
    float s0 = v0 * w[k0 * 2]     + v1 * w[(k0 + 1) * 2]     + v2 * w[(k0 + 2) * 2]     + v3 * w[(k0 + 3) * 2];
    float s1 = v0 * w[k0 * 2 + 1] + v1 * w[(k0 + 1) * 2 + 1] + v2 * w[(k0 + 2) * 2 + 1] + v3 * w[(k0 + 3) * 2 + 1];
    for (int off = 32; off; off >>= 1) {
        s0 += __shfl_xor(s0, off);
        s1 += __shfl_xor(s1, off);
    }
    if (lane == 0) {
        s0 += ldf(bo2, 0, f32);
        s1 += ldf(bo2, 1, f32);
        if (f32) {
            ((float*)out)[(size_t)node * 2]     = s0;
            ((float*)out)[(size_t)node * 2 + 1] = s1;
        } else {
            ((unsigned short*)out)[(size_t)node * 2]     = f2bf(s0);
            ((unsigned short*)out)[(size_t)node * 2 + 1] = f2bf(s1);
        }
    }
}

// ---------------------------------------------------------------------------
extern "C" void kernel_launch(void* const* d_in, const int* in_sizes, int n_in,
                              void* d_out, int out_size, void* d_ws, size_t ws_size,
                              hipStream_t stream)
{
    (void)n_in; (void)out_size; (void)ws_size;
    const void* des   = d_in[0];
    const void* tweet = d_in[1];
    const void* nump  = d_in[2];
    const void* catp  = d_in[3];
    const int*  ei    = (const int*)d_in[4];
    const int*  et    = (const int*)d_in[5];
    const void* Wd  = d_in[6];
    const void* bd  = d_in[7];
    const void* Wt  = d_in[8];
    const void* bt  = d_in[9];
    const void* Wn  = d_in[10];
    const void* bn  = d_in[11];
    const void* Wc  = d_in[12];
    const void* bc  = d_in[13];
    const void* Wi  = d_in[14];
    const void* bi  = d_in[15];
    const void* rel1  = d_in[16];
    const void* root1 = d_in[17];
    const void* bias1 = d_in[18];
    const void* rel2  = d_in[19];
    const void* root2 = d_in[20];
    const void* bias2 = d_in[21];
    const void* Wo1 = d_in[22];
    const void* bo1 = d_in[23];
    const void* Wo2 = d_in[24];
    const void* bo2 = d_in[25];

    const int N = in_sizes[0] / 768;
    const int E = in_sizes[5];

    char* ws = (char*)d_ws;
    size_t off = 0;
    auto alloc = [&](size_t bytes) -> char* {
        char* p = ws + off;
        off += (bytes + 255) & ~(size_t)255;
        return p;
    };
    unsigned short* B0 = (unsigned short*)alloc((size_t)N * 256 * 2);  // xcat / y1 / z
    unsigned short* B1 = (unsigned short*)alloc((size_t)N * 256 * 2);  // x / y2
    unsigned short* B2 = (unsigned short*)alloc((size_t)N * 256 * 2);  // m0
    unsigned short* B3 = (unsigned short*)alloc((size_t)N * 256 * 2);  // m1
    unsigned short* WdT  = (unsigned short*)alloc(64 * 768 * 2);
    unsigned short* WtT  = (unsigned short*)alloc(64 * 768 * 2);
    unsigned short* WiT  = (unsigned short*)alloc(256 * 256 * 2);
    unsigned short* Wo1T = (unsigned short*)alloc(256 * 256 * 2);
    unsigned short* BT1  = (unsigned short*)alloc(256 * 768 * 2);
    unsigned short* BT2  = (unsigned short*)alloc(256 * 768 * 2);
    unsigned short* bias_bf = (unsigned short*)alloc(1152 * 2);
    unsigned short* bd_bf = bias_bf;          // 64
    unsigned short* bt_bf = bias_bf + 64;     // 64
    unsigned short* bi_bf = bias_bf + 128;    // 256
    unsigned short* b1_bf = bias_bf + 384;    // 256
    unsigned short* b2_bf = bias_bf + 640;    // 256
    unsigned short* bo1_bf = bias_bf + 896;   // 256
    int* dflag  = (int*)alloc(4);
    int* cnt2   = (int*)alloc((size_t)2 * N * 4);   // must stay adjacent to cursor
    int* cursor = (int*)alloc((size_t)N * 4);
    int* rowptr = (int*)alloc((size_t)(N + 1) * 4);
    int* bsum   = (int*)alloc(64 * 4);
    int* bofs   = (int*)alloc(64 * 4);
    int* sorted = (int*)alloc((size_t)E * 4);

    // zero only cnt2 + cursor (rowptr/bsum/bofs/sorted are fully overwritten)
    size_t zlen = (size_t)(((char*)cursor + (size_t)N * 4) - (char*)cnt2);
    hipMemsetAsync(cnt2, 0, zlen, stream);

    // dtype detect (must precede all flag-readers)
    k_detect<<<1, 256, 0, stream>>>((const unsigned short*)des, dflag);

    // weight prep
    t_cvt<<<(768 * 64 + 255) / 256, 256, 0, stream>>>(Wd, WdT, 768, 64, dflag);
    t_cvt<<<(768 * 64 + 255) / 256, 256, 0, stream>>>(Wt, WtT, 768, 64, dflag);
    t_cvt<<<(256 * 256 + 255) / 256, 256, 0, stream>>>(Wi, WiT, 256, 256, dflag);
    t_cvt<<<(256 * 256 + 255) / 256, 256, 0, stream>>>(Wo1, Wo1T, 256, 256, dflag);
    build_bt<<<(256 * 768 + 255) / 256, 256, 0, stream>>>(root1, rel1, BT1, 256, dflag);
    build_bt<<<(256 * 768 + 255) / 256, 256, 0, stream>>>(root2, rel2, BT2, 256, dflag);
    k_biases<<<1, 256, 0, stream>>>(bd, bt, bi, bias1, bias2, bo1, bias_bf, dflag);

    // CSR build
    int eb = (E + 255) / 256;
    k_hist<<<eb, 256, 0, stream>>>(ei, et, cnt2, N, E);
    int nb = (N + 1023) / 1024;
    k_scan1<<<nb, 256, 0, stream>>>(cnt2, rowptr, bsum, N);
    k_scan2<<<1, 64, 0, stream>>>(bsum, bofs, nb);
    k_scan3<<<(N + 255) / 256, 256, 0, stream>>>(rowptr, bofs, N);
    k_fill<<<eb, 256, 0, stream>>>(ei, et, rowptr, cursor, sorted, N, E);

    // fused feature encode: y=0 des->cols 0..63, y=1 tweet->cols 64..127
    dim3 gEnc((N + 127) / 128, 2);
    gemm_nt<64, true><<<gEnc, 256, 0, stream>>>(des, des, des, 0, 256, 512, 768,
                                                WdT, 768, B0, 256, bd_bf, N, 768, 1, dflag,
                                                tweet, WtT, B0 + 64, bt_bf);
    k_small<<<(N + 127) / 128, 256, 0, stream>>>(nump, catp, Wn, bn, Wc, bc, B0, N, dflag);

    // x = lrelu(xcat @ Wi + bi) -> B1
    dim3 g128((N + 127) / 128, 2);
    gemm_nt<128, false><<<g128, 256, 0, stream>>>(B0, B0, B0, 0, 0, 0, 256, WiT, 256,
                                                  B1, 256, bi_bf, N, 256, 1, nullptr);

    // RGCN layer 1: aggregate x (B1) -> B2, B3; fused K=768 GEMM -> B0
    int ab = (N + 3) / 4;
    k_agg<<<ab, 256, 0, stream>>>(B1, B2, B3, N, rowptr, cnt2, sorted);
    gemm_nt<128, false><<<g128, 256, 0, stream>>>(B1, B2, B3, 0, 0, 0, 256, BT1, 768,
                                                  B0, 256, b1_bf, N, 768, 0, nullptr);

    // RGCN layer 2: aggregate y1 (B0) -> B2, B3; GEMM -> B1
    k_agg<<<ab, 256, 0, stream>>>(B0, B2, B3, N, rowptr, cnt2, sorted);
    gemm_nt<128, false><<<g128, 256, 0, stream>>>(B0, B2, B3, 0, 0, 0, 256, BT2, 768,
                                                  B1, 256, b2_bf, N, 768, 0, nullptr);

    // z = lrelu(y2 @ Wo1 + bo1) -> B0
    gemm_nt<128, false><<<g128, 256, 0, stream>>>(B1, B1, B1, 0, 0, 0, 256, Wo1T, 256,
                                                  B0, 256, bo1_bf, N, 256, 1, nullptr);

    // out = z @ Wo2 + bo2
    k_final<<<ab, 256, 0, stream>>>(B0, Wo2, bo2, d_out, N, dflag);
}

// Round 5
// 752.771 us; speedup vs baseline: 1.1474x; 1.0888x over previous
//
#include <hip/hip_runtime.h>
#include <stdint.h>

// ---------- bf16 helpers (raw ushort storage) ----------
__device__ __forceinline__ float bf2f(unsigned short h) {
    union { unsigned int u; float f; } x;
    x.u = ((unsigned int)h) << 16;
    return x.f;
}
__device__ __forceinline__ unsigned short f2bf(float f) {
    union { float f; unsigned int u; } x;
    x.f = f;
    unsigned int u = x.u;
    unsigned int r = (u + 0x7FFFu + ((u >> 16) & 1u)) >> 16;  // RNE
    return (unsigned short)r;
}
// pack two fp32 -> bf16x2 (round-half-up; differs from RNE only at exact ties)
__device__ __forceinline__ unsigned pk2(float a, float b) {
    unsigned ua = __float_as_uint(a) + 0x8000u;
    unsigned ub = __float_as_uint(b) + 0x8000u;
    return __builtin_amdgcn_perm(ub, ua, 0x07060302);  // D = [ua.hi16 | ub.hi16]
}

typedef __attribute__((ext_vector_type(8))) short short8;
typedef __attribute__((ext_vector_type(4))) float floatx4;

// ---------------------------------------------------------------------------
// Streaming encode GEMM: C[:,set*64 .. +64) = lrelu(A[N,768](fp32) @ Bt^T + b)
// B held in LDS (two K-halves of 384, padded stride 392 -> 50 KB, 2 blocks/CU).
// 512 threads = 8 waves; each wave owns up to 2 row-groups of 16; A streamed
// global->reg with prefetch depth 2; NO barriers in the K-loop.
// ---------------------------------------------------------------------------
__global__ __launch_bounds__(512) void k_encode(
    const float* __restrict__ Ades, const float* __restrict__ Atw,
    const unsigned short* __restrict__ BtDes, const unsigned short* __restrict__ BtTw,
    const unsigned short* __restrict__ bias_bf,  // [bd 64][bt 64]
    unsigned short* __restrict__ C, int M)
{
    __shared__ unsigned short Bs[64 * 392];  // 50176 B
    const int set = blockIdx.y;
    const float* A = set ? Atw : Ades;
    const unsigned short* Bt = set ? BtTw : BtDes;
    const unsigned short* bias = bias_bf + set * 64;
    const int colofs = set * 64;
    const int tid  = threadIdx.x;
    const int wave = tid >> 6, lane = tid & 63;
    const int quad = lane >> 4, l16 = lane & 15;
    const int ngroups = (M + 15) >> 4;

    const int g0 = blockIdx.x * 8 + wave;          // 0..2047
    const int g1 = g0 + (int)(gridDim.x * 8);      // second group
    const bool h1 = g1 < ngroups;
    int r0 = g0 * 16 + l16; if (r0 > M - 1) r0 = M - 1;
    int r1g = h1 ? g1 * 16 + l16 : r0; if (r1g > M - 1) r1g = M - 1;

    floatx4 acc0[4], acc1[4];
#pragma unroll
    for (int t = 0; t < 4; t++) {
        acc0[t] = (floatx4){0.f, 0.f, 0.f, 0.f};
        acc1[t] = (floatx4){0.f, 0.f, 0.f, 0.f};
    }

    const bool act0 = g0 < ngroups;

#pragma unroll
    for (int h = 0; h < 2; h++) {
        // stage B k-half h: rows n=0..63, k in [h*384, h*384+384)
        if (h) __syncthreads();
        for (int c = tid; c < 3072; c += 512) {
            int n = c / 48, kc = (c - n * 48) * 8;
            *(uint4*)&Bs[n * 392 + kc] = ((const uint4*)Bt)[n * 96 + h * 48 + (c - n * 48)];
        }
        __syncthreads();
        if (!act0) continue;

        const float* a0 = A + (size_t)r0 * 768 + h * 384 + quad * 8;
        const float* a1 = A + (size_t)r1g * 768 + h * 384 + quad * 8;
        float4 c0a = *(const float4*)(a0);
        float4 c0b = *(const float4*)(a0 + 4);
        float4 c1a = *(const float4*)(a1);
        float4 c1b = *(const float4*)(a1 + 4);
        float4 n0a = *(const float4*)(a0 + 32);
        float4 n0b = *(const float4*)(a0 + 36);
        float4 n1a = *(const float4*)(a1 + 32);
        float4 n1b = *(const float4*)(a1 + 36);

        for (int s = 0; s < 12; s++) {
            short8 af0, af1;
            unsigned* u0 = (unsigned*)&af0;
            unsigned* u1 = (unsigned*)&af1;
            u0[0] = pk2(c0a.x, c0a.y); u0[1] = pk2(c0a.z, c0a.w);
            u0[2] = pk2(c0b.x, c0b.y); u0[3] = pk2(c0b.z, c0b.w);
            u1[0] = pk2(c1a.x, c1a.y); u1[1] = pk2(c1a.z, c1a.w);
            u1[2] = pk2(c1b.x, c1b.y); u1[3] = pk2(c1b.z, c1b.w);
            c0a = n0a; c0b = n0b; c1a = n1a; c1b = n1b;
            if (s < 10) {
                n0a = *(const float4*)(a0 + (s + 2) * 32);
                n0b = *(const float4*)(a0 + (s + 2) * 32 + 4);
                n1a = *(const float4*)(a1 + (s + 2) * 32);
                n1b = *(const float4*)(a1 + (s + 2) * 32 + 4);
            }
            int kb = s * 32 + quad * 8;
#pragma unroll
            for (int t = 0; t < 4; t++) {
                short8 bfr = *(const short8*)&Bs[(t * 16 + l16) * 392 + kb];
                acc0[t] = __builtin_amdgcn_mfma_f32_16x16x32_bf16(af0, bfr, acc0[t], 0, 0, 0);
                acc1[t] = __builtin_amdgcn_mfma_f32_16x16x32_bf16(af1, bfr, acc1[t], 0, 0, 0);
            }
        }
    }

    // epilogue: C/D layout col = lane&15 (within n-tile), row = quad*4 + reg
    if (act0) {
#pragma unroll
        for (int t = 0; t < 4; t++) {
            float bv = bf2f(bias[t * 16 + l16]);
#pragma unroll
            for (int r = 0; r < 4; r++) {
                int row = g0 * 16 + quad * 4 + r;
                if (row < M) {
                    float v = acc0[t][r] + bv;
                    v = v > 0.f ? v : 0.01f * v;
                    C[(size_t)row * 256 + colofs + t * 16 + l16] = f2bf(v);
                }
                if (h1) {
                    int rw = g1 * 16 + quad * 4 + r;
                    if (rw < M) {
                        float v = acc1[t][r] + bv;
                        v = v > 0.f ? v : 0.01f * v;
                        C[(size_t)rw * 256 + colofs + t * 16 + l16] = f2bf(v);
                    }
                }
            }
        }
    }
}

// ---------------------------------------------------------------------------
// Tiled MFMA GEMM (bf16 A in up to three 256-col parts).
// BM=128, BK=64, 256 threads = 4 waves, BN=128 -> 4x4 MFMA per wave.
// ---------------------------------------------------------------------------
__global__ __launch_bounds__(256) void gemm_nt(
    const unsigned short* __restrict__ A0, const unsigned short* __restrict__ A1,
    const unsigned short* __restrict__ A2, int lda,
    const unsigned short* __restrict__ Bt, int ldb,
    unsigned short* __restrict__ C, int ldc,
    const unsigned short* __restrict__ bias,
    int M, int K, int act)
{
    constexpr int BM = 128, BN = 128, BK = 64;
    const int tid  = threadIdx.x;
    const int wave = tid >> 6;
    const int lane = tid & 63;
    const int quad = lane >> 4;
    const int l16  = lane & 15;
    const int m0   = blockIdx.x * BM;
    const int n0   = blockIdx.y * BN;
    const int wm   = (wave & 1) * 64;
    const int wn   = (wave >> 1) * 64;

    __shared__ short8 As[8 * (BM + 2)];
    __shared__ short8 Bs[8 * (BN + 2)];

    floatx4 acc[4][4];
#pragma unroll
    for (int i = 0; i < 4; i++)
#pragma unroll
        for (int j = 0; j < 4; j++) acc[i][j] = (floatx4){0.f, 0.f, 0.f, 0.f};

    for (int kt = 0; kt < K; kt += BK) {
        const unsigned short* Ap = (kt < 256) ? A0 : (kt < 512) ? A1 : A2;
        const int ko = kt & 255;
#pragma unroll
        for (int c = 0; c < 4; c++) {
            int lin = c * 256 + tid;
            int row = lin >> 3, kq = lin & 7;
            int gr = m0 + row; if (gr > M - 1) gr = M - 1;
            As[kq * (BM + 2) + row] = *(const short8*)(Ap + (size_t)gr * lda + ko + kq * 8);
        }
#pragma unroll
        for (int c = 0; c < 4; c++) {
            int lin = c * 256 + tid;
            int n = lin >> 3, kq = lin & 7;
            Bs[kq * (BN + 2) + n] = *(const short8*)(Bt + (size_t)(n0 + n) * ldb + kt + kq * 8);
        }
        __syncthreads();
#pragma unroll
        for (int s = 0; s < 2; s++) {
            short8 af[4], bfr[4];
#pragma unroll
            for (int i = 0; i < 4; i++)
                af[i] = As[(s * 4 + quad) * (BM + 2) + wm + i * 16 + l16];
#pragma unroll
            for (int j = 0; j < 4; j++)
                bfr[j] = Bs[(s * 4 + quad) * (BN + 2) + wn + j * 16 + l16];
#pragma unroll
            for (int i = 0; i < 4; i++)
#pragma unroll
                for (int j = 0; j < 4; j++)
                    acc[i][j] = __builtin_amdgcn_mfma_f32_16x16x32_bf16(
                        af[i], bfr[j], acc[i][j], 0, 0, 0);
        }
        __syncthreads();
    }

#pragma unroll
    for (int j = 0; j < 4; j++) {
        int gc = n0 + wn + j * 16 + l16;
        float bv = bias ? bf2f(bias[gc]) : 0.f;
#pragma unroll
        for (int i = 0; i < 4; i++) {
            int grb = m0 + wm + i * 16 + quad * 4;
#pragma unroll
            for (int r = 0; r < 4; r++) {
                int gr = grb + r;
                if (gr < M) {
                    float v = acc[i][j][r] + bv;
                    if (act) v = v > 0.f ? v : 0.01f * v;
                    C[(size_t)gr * ldc + gc] = f2bf(v);
                }
            }
        }
    }
}

// ---------- fused weight prep (all fp32 -> bf16) ----------
__global__ void k_prep(const float* __restrict__ Wd, const float* __restrict__ Wt,
                       const float* __restrict__ Wi, const float* __restrict__ Wo1,
                       const float* __restrict__ root1, const float* __restrict__ rel1,
                       const float* __restrict__ root2, const float* __restrict__ rel2,
                       const float* __restrict__ bd, const float* __restrict__ bt,
                       const float* __restrict__ bi, const float* __restrict__ b1,
                       const float* __restrict__ b2, const float* __restrict__ bo1,
                       unsigned short* __restrict__ WdT, unsigned short* __restrict__ WtT,
                       unsigned short* __restrict__ WiT, unsigned short* __restrict__ Wo1T,
                       unsigned short* __restrict__ BT1, unsigned short* __restrict__ BT2,
                       unsigned short* __restrict__ bias_bf)
{
    int i = blockIdx.x * 256 + threadIdx.x;
    if (i < 49152) { int r = i >> 6, c = i & 63; WdT[c * 768 + r] = f2bf(Wd[i]); return; }
    i -= 49152;
    if (i < 49152) { int r = i >> 6, c = i & 63; WtT[c * 768 + r] = f2bf(Wt[i]); return; }
    i -= 49152;
    if (i < 65536) { int r = i >> 8, c = i & 255; WiT[c * 256 + r] = f2bf(Wi[i]); return; }
    i -= 65536;
    if (i < 65536) { int r = i >> 8, c = i & 255; Wo1T[c * 256 + r] = f2bf(Wo1[i]); return; }
    i -= 65536;
    if (i < 196608) {
        int k = i % 768, n = i / 768;
        BT1[i] = f2bf(k < 256 ? root1[k * 256 + n] : rel1[(k - 256) * 256 + n]);
        return;
    }
    i -= 196608;
    if (i < 196608) {
        int k = i % 768, n = i / 768;
        BT2[i] = f2bf(k < 256 ? root2[k * 256 + n] : rel2[(k - 256) * 256 + n]);
        return;
    }
    i -= 196608;
    if (i < 1152) {
        const float* p; int off;
        if (i < 64)       { p = bd;  off = i; }
        else if (i < 128) { p = bt;  off = i - 64; }
        else if (i < 384) { p = bi;  off = i - 128; }
        else if (i < 640) { p = b1;  off = i - 384; }
        else if (i < 896) { p = b2;  off = i - 640; }
        else              { p = bo1; off = i - 896; }
        bias_bf[i] = f2bf(p[off]);
    }
}

// ---------- CSR build ----------
__global__ void k_hist(const int* __restrict__ ei, const int* __restrict__ et,
                       int* cnt2, int N, int E) {
    int e = blockIdx.x * 256 + threadIdx.x;
    if (e < E) {
        int dst = ei[E + e];
        int t = et[e] & 1;
        if ((unsigned)dst < (unsigned)N) atomicAdd(&cnt2[t * N + dst], 1);
    }
}

__global__ void k_scan1(const int* __restrict__ cnt2, int* rowptr, int* bsum, int N) {
    __shared__ int sh[256];
    int t = threadIdx.x;
    int base = blockIdx.x * 1024 + t * 4;
    int v[4];
    int s = 0;
#pragma unroll
    for (int k = 0; k < 4; k++) {
        int idx = base + k;
        v[k] = (idx < N) ? (cnt2[idx] + cnt2[N + idx]) : 0;
        s += v[k];
    }
    sh[t] = s;
    __syncthreads();
    for (int off = 1; off < 256; off <<= 1) {
        int x = 0;
        if (t >= off) x = sh[t - off];
        __syncthreads();
        if (t >= off) sh[t] += x;
        __syncthreads();
    }
    int excl = sh[t] - s;
    int run = excl;
#pragma unroll
    for (int k = 0; k < 4; k++) {
        int idx = base + k;
        if (idx < N) rowptr[idx] = run;
        run += v[k];
    }
    if (t == 255) bsum[blockIdx.x] = sh[255];
}

__global__ void k_scan2(const int* __restrict__ bsum, int* bofs, int nb) {
    int t = threadIdx.x;  // 64
    int v = (t < nb) ? bsum[t] : 0;
    int orig = v;
    for (int off = 1; off < 64; off <<= 1) {
        int x = __shfl_up(v, off);
        if (t >= off) v += x;
    }
    if (t < nb) bofs[t] = v - orig;
}

__global__ void k_scan3(int* rowptr, const int* __restrict__ bofs, int N) {
    int i = blockIdx.x * 256 + threadIdx.x;
    if (i < N) rowptr[i] += bofs[i >> 10];
}

__global__ void k_fill(const int* __restrict__ ei, const int* __restrict__ et,
                       const int* __restrict__ rowptr, int* cursor, int* sorted,
                       int N, int E) {
    int e = blockIdx.x * 256 + threadIdx.x;
    if (e < E) {
        int src = ei[e];
        int dst = ei[E + e];
        int t = et[e] & 1;
        if ((unsigned)dst < (unsigned)N && (unsigned)src < (unsigned)N) {
            int pos = rowptr[dst] + atomicAdd(&cursor[dst], 1);
            sorted[pos] = src | (t << 24);
        }
    }
}

// ---------- aggregation: one wave per node, 2 edges/iter, 4 loads in flight ----------
__global__ __launch_bounds__(256) void k_agg(
    const unsigned short* __restrict__ x,
    unsigned short* __restrict__ m0,
    unsigned short* __restrict__ m1,
    int N,
    const int* __restrict__ rowptr, const int* __restrict__ cnt2,
    const int* __restrict__ sorted)
{
    int wave = threadIdx.x >> 6;
    int lane = threadIdx.x & 63;
    int half = lane >> 5;
    int l32  = lane & 31;
    int node = blockIdx.x * 4 + wave;
    if (node >= N) return;

    int start = rowptr[node];
    int c0 = cnt2[node], c1 = cnt2[N + node];
    int deg = c0 + c1;

    float a0[8] = {0,0,0,0,0,0,0,0};
    float a1[8] = {0,0,0,0,0,0,0,0};

    for (int b = 0; b < deg; b += 64) {
        int rem = deg - b; if (rem > 64) rem = 64;
        int p = 0;
        if (lane < rem) p = sorted[start + b + lane];
        int iters = (rem + 1) >> 1;
        for (int t = 0; t < iters; t += 2) {
            int e0 = 2 * t + half;
            int e1 = e0 + 2;
            int q0 = __shfl(p, e0 < 64 ? e0 : 63);
            int q1 = __shfl(p, e1 < 64 ? e1 : 63);
            bool v0ok = e0 < rem;
            bool v1ok = e1 < rem;
            int s0 = q0 & 0xFFFFFF; if (s0 >= N) s0 = 0;
            int s1 = q1 & 0xFFFFFF; if (s1 >= N) s1 = 0;
            uint4 r0 = *((const uint4*)(x + (size_t)s0 * 256) + l32);
            uint4 r1 = *((const uint4*)(x + (size_t)s1 * 256) + l32);
            if (v0ok) {
                float f[8];
                f[0] = bf2f((unsigned short)(r0.x & 0xFFFFu)); f[1] = bf2f((unsigned short)(r0.x >> 16));
                f[2] = bf2f((unsigned short)(r0.y & 0xFFFFu)); f[3] = bf2f((unsigned short)(r0.y >> 16));
                f[4] = bf2f((unsigned short)(r0.z & 0xFFFFu)); f[5] = bf2f((unsigned short)(r0.z >> 16));
                f[6] = bf2f((unsigned short)(r0.w & 0xFFFFu)); f[7] = bf2f((unsigned short)(r0.w >> 16));
                if ((q0 >> 24) & 1) {
#pragma unroll
                    for (int k = 0; k < 8; k++) a1[k] += f[k];
                } else {
#pragma unroll
                    for (int k = 0; k < 8; k++) a0[k] += f[k];
                }
            }
            if (v1ok) {
                float f[8];
                f[0] = bf2f((unsigned short)(r1.x & 0xFFFFu)); f[1] = bf2f((unsigned short)(r1.x >> 16));
                f[2] = bf2f((unsigned short)(r1.y & 0xFFFFu)); f[3] = bf2f((unsigned short)(r1.y >> 16));
                f[4] = bf2f((unsigned short)(r1.z & 0xFFFFu)); f[5] = bf2f((unsigned short)(r1.z >> 16));
                f[6] = bf2f((unsigned short)(r1.w & 0xFFFFu)); f[7] = bf2f((unsigned short)(r1.w >> 16));
                if ((q1 >> 24) & 1) {
#pragma unroll
                    for (int k = 0; k < 8; k++) a1[k] += f[k];
                } else {
#pragma unroll
                    for (int k = 0; k < 8; k++) a0[k] += f[k];
                }
            }
        }
    }
#pragma unroll
    for (int k = 0; k < 8; k++) {
        a0[k] += __shfl_xor(a0[k], 32);
        a1[k] += __shfl_xor(a1[k], 32);
    }
    float i0 = c0 > 0 ? 1.f / (float)c0 : 0.f;
    float i1 = c1 > 0 ? 1.f / (float)c1 : 0.f;
    uint4 o;
    if (half == 0) {
        o.x = (unsigned)f2bf(a0[0] * i0) | ((unsigned)f2bf(a0[1] * i0) << 16);
        o.y = (unsigned)f2bf(a0[2] * i0) | ((unsigned)f2bf(a0[3] * i0) << 16);
        o.z = (unsigned)f2bf(a0[4] * i0) | ((unsigned)f2bf(a0[5] * i0) << 16);
        o.w = (unsigned)f2bf(a0[6] * i0) | ((unsigned)f2bf(a0[7] * i0) << 16);
        *((uint4*)(m0 + (size_t)node * 256) + l32) = o;
    } else {
        o.x = (unsigned)f2bf(a1[0] * i1) | ((unsigned)f2bf(a1[1] * i1) << 16);
        o.y = (unsigned)f2bf(a1[2] * i1) | ((unsigned)f2bf(a1[3] * i1) << 16);
        o.z = (unsigned)f2bf(a1[4] * i1) | ((unsigned)f2bf(a1[5] * i1) << 16);
        o.w = (unsigned)f2bf(a1[6] * i1) | ((unsigned)f2bf(a1[7] * i1) << 16);
        *((uint4*)(m1 + (size_t)node * 256) + l32) = o;
    }
}

// ---------- small-K encode (num K=5 -> cols 128..191, cat K=3 -> 192..255) ----------
__global__ void k_small(const float* __restrict__ num, const float* __restrict__ cat,
                        const float* __restrict__ Wn, const float* __restrict__ bnp,
                        const float* __restrict__ Wc, const float* __restrict__ bcp,
                        unsigned short* __restrict__ xcat, int N)
{
    __shared__ float wn[320], wc[192], bns[64], bcs[64];
    int t = threadIdx.x;
    for (int i = t; i < 320; i += 256) wn[i] = Wn[i];
    for (int i = t; i < 192; i += 256) wc[i] = Wc[i];
    if (t < 64) { bns[t] = bnp[t]; bcs[t] = bcp[t]; }
    __syncthreads();

    int node = blockIdx.x * 128 + (t >> 1);
    int half = t & 1;
    if (node >= N) return;
    if (half == 0) {
        float in5[5];
#pragma unroll
        for (int i = 0; i < 5; i++) in5[i] = num[(size_t)node * 5 + i];
        unsigned short* orow = xcat + (size_t)node * 256 + 128;
#pragma unroll 4
        for (int c = 0; c < 64; c++) {
            float v = bns[c];
#pragma unroll
            for (int i = 0; i < 5; i++) v += in5[i] * wn[i * 64 + c];
            v = v > 0.f ? v : 0.01f * v;
            orow[c] = f2bf(v);
        }
    } else {
        float in3[3];
#pragma unroll
        for (int i = 0; i < 3; i++) in3[i] = cat[(size_t)node * 3 + i];
        unsigned short* orow = xcat + (size_t)node * 256 + 192;
#pragma unroll 4
        for (int c = 0; c < 64; c++) {
            float v = bcs[c];
#pragma unroll
            for (int i = 0; i < 3; i++) v += in3[i] * wc[i * 64 + c];
            v = v > 0.f ? v : 0.01f * v;
            orow[c] = f2bf(v);
        }
    }
}

// ---------- final projection: out[N,2](fp32) = z[N,256] @ Wo2[256,2] + bo2 ----------
__global__ __launch_bounds__(256) void k_final(
    const unsigned short* __restrict__ z,
    const float* __restrict__ Wo2, const float* __restrict__ bo2,
    float* __restrict__ out, int N)
{
    __shared__ float w[512];
    int t = threadIdx.x;
    for (int i = t; i < 512; i += 256) w[i] = Wo2[i];
    __syncthreads();
    int wave = t >> 6, lane = t & 63;
    int node = blockIdx.x * 4 + wave;
    if (node >= N) return;
    uint2 raw = *((const uint2*)(z + (size_t)node * 256) + lane);
    float v0 = bf2f((unsigned short)(raw.x & 0xFFFFu));
    float v1 = bf2f((unsigned short)(raw.x >> 16));
    float v2 = bf2f((unsigned short)(raw.y & 0xFFFFu));
    float v3 = bf2f((unsigned short)(raw.y >> 16));
    int k0 = lane * 4;
    float s0 = v0 * w[k0 * 2]     + v1 * w[(k0 + 1) * 2]     + v2 * w[(k0 + 2) * 2]     + v3 * w[(k0 + 3) * 2];
    float s1 = v0 * w[k0 * 2 + 1] + v1 * w[(k0 + 1) * 2 + 1] + v2 * w[(k0 + 2) * 2 + 1] + v3 * w[(k0 + 3) * 2 + 1];
    for (int off = 32; off; off >>= 1) {
        s0 += __shfl_xor(s0, off);
        s1 += __shfl_xor(s1, off);
    }
    if (lane == 0) {
        out[(size_t)node * 2]     = s0 + bo2[0];
        out[(size_t)node * 2 + 1] = s1 + bo2[1];
    }
}

// ---------------------------------------------------------------------------
extern "C" void kernel_launch(void* const* d_in, const int* in_sizes, int n_in,
                              void* d_out, int out_size, void* d_ws, size_t ws_size,
                              hipStream_t stream)
{
    (void)n_in; (void)out_size; (void)ws_size;
    const float* des   = (const float*)d_in[0];
    const float* tweet = (const float*)d_in[1];
    const float* nump  = (const float*)d_in[2];
    const float* catp  = (const float*)d_in[3];
    const int*   ei    = (const int*)d_in[4];
    const int*   et    = (const int*)d_in[5];
    const float* Wd  = (const float*)d_in[6];
    const float* bd  = (const float*)d_in[7];
    const float* Wt  = (const float*)d_in[8];
    const float* bt  = (const float*)d_in[9];
    const float* Wn  = (const float*)d_in[10];
    const float* bn  = (const float*)d_in[11];
    const float* Wc  = (const float*)d_in[12];
    const float* bc  = (const float*)d_in[13];
    const float* Wi  = (const float*)d_in[14];
    const float* bi  = (const float*)d_in[15];
    const float* rel1  = (const float*)d_in[16];
    const float* root1 = (const float*)d_in[17];
    const float* bias1 = (const float*)d_in[18];
    const float* rel2  = (const float*)d_in[19];
    const float* root2 = (const float*)d_in[20];
    const float* bias2 = (const float*)d_in[21];
    const float* Wo1 = (const float*)d_in[22];
    const float* bo1 = (const float*)d_in[23];
    const float* Wo2 = (const float*)d_in[24];
    const float* bo2 = (const float*)d_in[25];

    const int N = in_sizes[0] / 768;
    const int E = in_sizes[5];

    char* ws = (char*)d_ws;
    size_t off = 0;
    auto alloc = [&](size_t bytes) -> char* {
        char* p = ws + off;
        off += (bytes + 255) & ~(size_t)255;
        return p;
    };
    unsigned short* B0 = (unsigned short*)alloc((size_t)N * 256 * 2);  // xcat / y1 / z
    unsigned short* B1 = (unsigned short*)alloc((size_t)N * 256 * 2);  // x / y2
    unsigned short* B2 = (unsigned short*)alloc((size_t)N * 256 * 2);  // m0
    unsigned short* B3 = (unsigned short*)alloc((size_t)N * 256 * 2);  // m1
    unsigned short* WdT  = (unsigned short*)alloc(64 * 768 * 2);
    unsigned short* WtT  = (unsigned short*)alloc(64 * 768 * 2);
    unsigned short* WiT  = (unsigned short*)alloc(256 * 256 * 2);
    unsigned short* Wo1T = (unsigned short*)alloc(256 * 256 * 2);
    unsigned short* BT1  = (unsigned short*)alloc(256 * 768 * 2);
    unsigned short* BT2  = (unsigned short*)alloc(256 * 768 * 2);
    unsigned short* bias_bf = (unsigned short*)alloc(1152 * 2);
    unsigned short* bd_bf = bias_bf;          // 64
    unsigned short* bi_bf = bias_bf + 128;    // 256
    unsigned short* b1_bf = bias_bf + 384;    // 256
    unsigned short* b2_bf = bias_bf + 640;    // 256
    unsigned short* bo1_bf = bias_bf + 896;   // 256
    int* cnt2   = (int*)alloc((size_t)2 * N * 4);   // adjacent to cursor
    int* cursor = (int*)alloc((size_t)N * 4);
    int* rowptr = (int*)alloc((size_t)(N + 1) * 4);
    int* bsum   = (int*)alloc(64 * 4);
    int* bofs   = (int*)alloc(64 * 4);
    int* sorted = (int*)alloc((size_t)E * 4);

    // zero cnt2 + cursor
    size_t zlen = (size_t)(((char*)cursor + (size_t)N * 4) - (char*)cnt2);
    hipMemsetAsync(cnt2, 0, zlen, stream);

    // fused weight prep: 623744 elements
    k_prep<<<(623744 + 255) / 256, 256, 0, stream>>>(
        Wd, Wt, Wi, Wo1, root1, rel1, root2, rel2,
        bd, bt, bi, bias1, bias2, bo1,
        WdT, WtT, WiT, Wo1T, BT1, BT2, bias_bf);

    // CSR build
    int eb = (E + 255) / 256;
    k_hist<<<eb, 256, 0, stream>>>(ei, et, cnt2, N, E);
    int nb = (N + 1023) / 1024;
    k_scan1<<<nb, 256, 0, stream>>>(cnt2, rowptr, bsum, N);
    k_scan2<<<1, 64, 0, stream>>>(bsum, bofs, nb);
    k_scan3<<<(N + 255) / 256, 256, 0, stream>>>(rowptr, bofs, N);
    k_fill<<<eb, 256, 0, stream>>>(ei, et, rowptr, cursor, sorted, N, E);

    // streaming feature encode -> B0 cols 0..127 (des 0..63, tweet 64..127)
    dim3 gEnc(256, 2);
    k_encode<<<gEnc, 512, 0, stream>>>(des, tweet, WdT, WtT, bd_bf, B0, N);
    k_small<<<(N + 127) / 128, 256, 0, stream>>>(nump, catp, Wn, bn, Wc, bc, B0, N);

    // x = lrelu(xcat @ Wi + bi) -> B1
    dim3 g128((N + 127) / 128, 2);
    gemm_nt<<<g128, 256, 0, stream>>>(B0, B0, B0, 256, WiT, 256, B1, 256, bi_bf, N, 256, 1);

    // RGCN layer 1: aggregate x (B1) -> B2, B3; fused K=768 GEMM -> B0
    int ab = (N + 3) / 4;
    k_agg<<<ab, 256, 0, stream>>>(B1, B2, B3, N, rowptr, cnt2, sorted);
    gemm_nt<<<g128, 256, 0, stream>>>(B1, B2, B3, 256, BT1, 768, B0, 256, b1_bf, N, 768, 0);

    // RGCN layer 2: aggregate y1 (B0) -> B2, B3; GEMM -> B1
    k_agg<<<ab, 256, 0, stream>>>(B0, B2, B3, N, rowptr, cnt2, sorted);
    gemm_nt<<<g128, 256, 0, stream>>>(B0, B2, B3, 256, BT2, 768, B1, 256, b2_bf, N, 768, 0);

    // z = lrelu(y2 @ Wo1 + bo1) -> B0
    gemm_nt<<<g128, 256, 0, stream>>>(B1, B1, B1, 256, Wo1T, 256, B0, 256, bo1_bf, N, 256, 1);

    // out = z @ Wo2 + bo2 (fp32)
    k_final<<<ab, 256, 0, stream>>>(B0, Wo2, bo2, (float*)d_out, N);
}